// Round 2
// baseline (278.288 us; speedup 1.0000x reference)
//
#include <hip/hip_runtime.h>
#include <hip/hip_bf16.h>
#include <math.h>

// ComplexProjection: out[b,r,p] = | sum_s complex(xr,xi)[b,r,s] * w[r,s,p] |
// B=32768, R=16, S=128, P=128. Memory-bound target (~770 MB => ~122us floor);
// bf16 MFMA for compute. R2: per-N-tile accumulation (8 live acc VGPRs),
// launch_bounds(256,4), vectorized conflict-free LDS staging, nt stores.

typedef __attribute__((ext_vector_type(8))) __bf16 bf16x8;
typedef __attribute__((ext_vector_type(4))) float f32x4;

#define B_TOT 32768
#define R_TOT 16
#define S_TOT 128
#define P_TOT 128
#define BLOCKS_PER_R 128
#define ROWS_PER_BLOCK 256  // B_TOT / BLOCKS_PER_R
#define RS (R_TOT * S_TOT)  // 2048: x row stride (floats)
#define RP (R_TOT * P_TOT)  // 2048: out row stride (floats)

__global__ __launch_bounds__(256, 4) void cproj_kernel(
    const float* __restrict__ x_real,
    const float* __restrict__ x_imag,
    const float* __restrict__ proj,
    float* __restrict__ out)
{
    // W[r] staged bf16, transposed [p][s], XOR-swizzled on 16B units:
    // elem(p, sc, j) = p*128 + ((sc ^ (p&7)) << 3) + j   (sc = s>>3, j = s&7)
    __shared__ __attribute__((aligned(16))) __bf16 wlds[S_TOT * P_TOT];

    const int tid = threadIdx.x;
    const int r   = blockIdx.x >> 7;
    const int br  = blockIdx.x & (BLOCKS_PER_R - 1);

    // ---- stage W[r] -> LDS ----
    // thread handles (p, sc) pairs: 8 coalesced fp32 loads (lanes span p),
    // one 16B bf16x8 ds_write to the swizzled slot (balanced bank phases).
    const float* wr = proj + (size_t)r * (S_TOT * P_TOT);
    #pragma unroll
    for (int i = 0; i < 8; ++i) {
        const int pair = tid + i * 256;
        const int p  = pair & 127;
        const int sc = pair >> 7;  // 0..15
        bf16x8 wv;
        #pragma unroll
        for (int j = 0; j < 8; ++j) {
            wv[j] = (__bf16)wr[(sc * 8 + j) * 128 + p];
        }
        *(bf16x8*)&wlds[p * 128 + ((sc ^ (p & 7)) << 3)] = wv;
    }
    __syncthreads();

    const int lane = tid & 63;
    const int wid  = tid >> 6;   // 0..3 waves
    const int m    = lane & 15;  // A row / B col / D col index
    const int g    = lane >> 4;  // 0..3 k-group / D row group
    const int b_base = br * ROWS_PER_BLOCK;

    for (int it = 0; it < 4; ++it) {
        const int b0  = b_base + it * 64 + wid * 16;  // this wave's 16-row strip
        const int row = b0 + m;
        const float* pr = x_real + (size_t)row * RS + r * S_TOT;
        const float* pi = x_imag + (size_t)row * RS + r * S_TOT;

        // A fragments: lane holds A[row][kk*32 + g*8 .. +7], converted to bf16
        bf16x8 ar[4], ai[4];
        #pragma unroll
        for (int kk = 0; kk < 4; ++kk) {
            const int kb = kk * 32 + g * 8;
            f32x4 f0 = *(const f32x4*)(pr + kb);
            f32x4 f1 = *(const f32x4*)(pr + kb + 4);
            f32x4 h0 = *(const f32x4*)(pi + kb);
            f32x4 h1 = *(const f32x4*)(pi + kb + 4);
            bf16x8 a, b;
            #pragma unroll
            for (int j = 0; j < 4; ++j) {
                a[j]     = (__bf16)f0[j];
                a[j + 4] = (__bf16)f1[j];
                b[j]     = (__bf16)h0[j];
                b[j + 4] = (__bf16)h1[j];
            }
            ar[kk] = a;
            ai[kk] = b;
        }

        // Per-N-tile accumulate + immediate store: only 8 acc VGPRs live.
        float* po = out + (size_t)(b0 + g * 4) * RP + r * P_TOT + m;
        #pragma unroll
        for (int n = 0; n < 8; ++n) {
            const int p = n * 16 + m;
            f32x4 cr = (f32x4)0.0f;
            f32x4 ci = (f32x4)0.0f;
            #pragma unroll
            for (int kk = 0; kk < 4; ++kk) {
                const int sb = kk * 4 + g;  // 16B-unit index along s
                const bf16x8 w =
                    *(const bf16x8*)&wlds[p * 128 + ((sb ^ (m & 7)) << 3)];
                cr = __builtin_amdgcn_mfma_f32_16x16x32_bf16(ar[kk], w, cr, 0, 0, 0);
                ci = __builtin_amdgcn_mfma_f32_16x16x32_bf16(ai[kk], w, ci, 0, 0, 0);
            }
            // D lane mapping (verified m89): col = lane&15, row = (lane>>4)*4 + j
            #pragma unroll
            for (int j = 0; j < 4; ++j) {
                float re = cr[j];
                float im = ci[j];
                __builtin_nontemporal_store(sqrtf(re * re + im * im),
                                            &po[(size_t)j * RP + n * 16]);
            }
        }
    }
}

extern "C" void kernel_launch(void* const* d_in, const int* in_sizes, int n_in,
                              void* d_out, int out_size, void* d_ws, size_t ws_size,
                              hipStream_t stream) {
    const float* x_real = (const float*)d_in[0];
    const float* x_imag = (const float*)d_in[1];
    const float* proj   = (const float*)d_in[2];
    float* out = (float*)d_out;

    dim3 grid(R_TOT * BLOCKS_PER_R);  // 2048 blocks
    dim3 block(256);
    cproj_kernel<<<grid, block, 0, stream>>>(x_real, x_imag, proj, out);
}

// Round 3
// 200.053 us; speedup vs baseline: 1.3911x; 1.3911x over previous
//
#include <hip/hip_runtime.h>
#include <hip/hip_bf16.h>
#include <math.h>

// ComplexProjection: out[b,r,p] = | sum_s complex(xr,xi)[b,r,s] * w[r,s,p] |
// B=32768, R=16, S=128, P=128. Memory-bound target (~770 MB => ~122us floor).
// R3: slab-dense block mapping (r = blockIdx&15 so co-scheduled blocks read
// complementary columns of the SAME row slab -> DRAM page locality),
// cross-strip load pipeline (next strip's raw f32x4 in flight during MFMA),
// plain stores (NT caused 1.7x write amplification in R2).

typedef __attribute__((ext_vector_type(8))) __bf16 bf16x8;
typedef __attribute__((ext_vector_type(4))) float f32x4;

#define B_TOT 32768
#define R_TOT 16
#define S_TOT 128
#define P_TOT 128
#define BLOCKS_PER_R 128
#define ROWS_PER_BLOCK 256
#define RS (R_TOT * S_TOT)  // 2048 floats: x row stride
#define RP (R_TOT * P_TOT)  // 2048 floats: out row stride

__global__ __launch_bounds__(256, 4) void cproj_kernel(
    const float* __restrict__ x_real,
    const float* __restrict__ x_imag,
    const float* __restrict__ proj,
    float* __restrict__ out)
{
    // W[r] staged bf16, transposed [p][s], XOR-swizzled on 16B units:
    // elem(p, sc, j) = p*128 + ((sc ^ (p&7)) << 3) + j   (sc = s>>3, j = s&7)
    __shared__ __attribute__((aligned(16))) __bf16 wlds[S_TOT * P_TOT];

    const int tid = threadIdx.x;
    const int r   = blockIdx.x & 15;        // co-scheduled blocks span all r
    const int br  = blockIdx.x >> 4;        // ...of the same 256-row slab

    const int lane = tid & 63;
    const int wid  = tid >> 6;   // 0..3 waves
    const int m    = lane & 15;  // A row / B col / D col index
    const int g    = lane >> 4;  // 0..3 k-group / D row group
    const int b_base = br * ROWS_PER_BLOCK;

    const float* pr_base = x_real + (size_t)(b_base + wid * 16 + m) * RS + r * S_TOT;
    const float* pi_base = x_imag + (size_t)(b_base + wid * 16 + m) * RS + r * S_TOT;

    // raw next-strip payload: 16 f32x4 = 64 VGPRs, kept in flight across compute
    f32x4 rawr[8], rawi[8];

#define LOAD_STRIP(it)                                                    \
    do {                                                                  \
        const float* pr_ = pr_base + (size_t)(it) * 64 * RS;              \
        const float* pi_ = pi_base + (size_t)(it) * 64 * RS;              \
        _Pragma("unroll")                                                 \
        for (int kk = 0; kk < 4; ++kk) {                                  \
            const int kb = kk * 32 + g * 8;                               \
            rawr[2 * kk]     = *(const f32x4*)(pr_ + kb);                 \
            rawr[2 * kk + 1] = *(const f32x4*)(pr_ + kb + 4);             \
            rawi[2 * kk]     = *(const f32x4*)(pi_ + kb);                 \
            rawi[2 * kk + 1] = *(const f32x4*)(pi_ + kb + 4);             \
        }                                                                 \
    } while (0)

    // issue strip 0 loads before W staging to hide startup latency
    LOAD_STRIP(0);

    // ---- stage W[r] -> LDS (coalesced fp32 reads, 16B swizzled bf16 writes)
    const float* wr = proj + (size_t)r * (S_TOT * P_TOT);
    #pragma unroll
    for (int i = 0; i < 8; ++i) {
        const int pair = tid + i * 256;
        const int p  = pair & 127;
        const int sc = pair >> 7;  // 0..15
        bf16x8 wv;
        #pragma unroll
        for (int j = 0; j < 8; ++j) {
            wv[j] = (__bf16)wr[(sc * 8 + j) * 128 + p];
        }
        *(bf16x8*)&wlds[p * 128 + ((sc ^ (p & 7)) << 3)] = wv;
    }
    __syncthreads();

    #pragma unroll
    for (int it = 0; it < 4; ++it) {
        // convert current strip raw -> bf16 fragments (raw regs then reusable)
        bf16x8 ar[4], ai[4];
        #pragma unroll
        for (int kk = 0; kk < 4; ++kk) {
            bf16x8 a, b;
            #pragma unroll
            for (int j = 0; j < 4; ++j) {
                a[j]     = (__bf16)rawr[2 * kk][j];
                a[j + 4] = (__bf16)rawr[2 * kk + 1][j];
                b[j]     = (__bf16)rawi[2 * kk][j];
                b[j + 4] = (__bf16)rawi[2 * kk + 1][j];
            }
            ar[kk] = a;
            ai[kk] = b;
        }

        // prefetch next strip while this strip computes
        if (it < 3) LOAD_STRIP(it + 1);

        const int b0 = b_base + it * 64 + wid * 16;
        float* po = out + (size_t)(b0 + g * 4) * RP + r * P_TOT + m;

        #pragma unroll
        for (int n = 0; n < 8; ++n) {
            const int p = n * 16 + m;
            f32x4 cr = (f32x4)0.0f;
            f32x4 ci = (f32x4)0.0f;
            #pragma unroll
            for (int kk = 0; kk < 4; ++kk) {
                const int sb = kk * 4 + g;
                const bf16x8 w =
                    *(const bf16x8*)&wlds[p * 128 + ((sb ^ (m & 7)) << 3)];
                cr = __builtin_amdgcn_mfma_f32_16x16x32_bf16(ar[kk], w, cr, 0, 0, 0);
                ci = __builtin_amdgcn_mfma_f32_16x16x32_bf16(ai[kk], w, ci, 0, 0, 0);
            }
            // D mapping (m89): col = lane&15, row = (lane>>4)*4 + j
            #pragma unroll
            for (int j = 0; j < 4; ++j) {
                float re = cr[j];
                float im = ci[j];
                po[(size_t)j * RP + n * 16] = sqrtf(re * re + im * im);
            }
        }
    }
#undef LOAD_STRIP
}

extern "C" void kernel_launch(void* const* d_in, const int* in_sizes, int n_in,
                              void* d_out, int out_size, void* d_ws, size_t ws_size,
                              hipStream_t stream) {
    const float* x_real = (const float*)d_in[0];
    const float* x_imag = (const float*)d_in[1];
    const float* proj   = (const float*)d_in[2];
    float* out = (float*)d_out;

    dim3 grid(R_TOT * BLOCKS_PER_R);  // 2048 blocks
    dim3 block(256);
    cproj_kernel<<<grid, block, 0, stream>>>(x_real, x_imag, proj, out);
}

// Round 4
// 174.731 us; speedup vs baseline: 1.5927x; 1.1449x over previous
//
#include <hip/hip_runtime.h>
#include <hip/hip_bf16.h>
#include <math.h>

// ComplexProjection: out[b,r,p] = | sum_s complex(xr,xi)[b,r,s] * w[r,s,p] |
// B=32768, R=16, S=128, P=128. Memory-bound target (~770 MB => ~122us floor).
// R4: restore the cross-strip prefetch that R3's compiler sank:
//   - __launch_bounds__(256, 3): ~170 VGPR budget so the 64-VGPR raw payload
//     can stay live across the MFMA n-loop (R3's (256,4) forced VGPR=64 ->
//     loads serialized at first use, 2.8 TB/s Little's-law ceiling).
//   - sched_barrier(0) fence around the prefetch load cluster so the
//     scheduler cannot sink the issues; the waitcnt still lands at first
//     use (next strip's convert), i.e. AFTER this strip's MFMAs.
// Keeps R3's slab-dense mapping (r = blockIdx&15) and plain stores.

typedef __attribute__((ext_vector_type(8))) __bf16 bf16x8;
typedef __attribute__((ext_vector_type(4))) float f32x4;

#define B_TOT 32768
#define R_TOT 16
#define S_TOT 128
#define P_TOT 128
#define BLOCKS_PER_R 128
#define ROWS_PER_BLOCK 256
#define RS (R_TOT * S_TOT)  // 2048 floats: x row stride
#define RP (R_TOT * P_TOT)  // 2048 floats: out row stride

__global__ __launch_bounds__(256, 3) void cproj_kernel(
    const float* __restrict__ x_real,
    const float* __restrict__ x_imag,
    const float* __restrict__ proj,
    float* __restrict__ out)
{
    // W[r] staged bf16, transposed [p][s], XOR-swizzled on 16B units:
    // elem(p, sc, j) = p*128 + ((sc ^ (p&7)) << 3) + j   (sc = s>>3, j = s&7)
    __shared__ __attribute__((aligned(16))) __bf16 wlds[S_TOT * P_TOT];

    const int tid = threadIdx.x;
    const int r   = blockIdx.x & 15;        // co-scheduled blocks span all r
    const int br  = blockIdx.x >> 4;        // ...of the same 256-row slab

    const int lane = tid & 63;
    const int wid  = tid >> 6;   // 0..3 waves
    const int m    = lane & 15;  // A row / B col / D col index
    const int g    = lane >> 4;  // 0..3 k-group / D row group
    const int b_base = br * ROWS_PER_BLOCK;

    const float* pr_base = x_real + (size_t)(b_base + wid * 16 + m) * RS + r * S_TOT;
    const float* pi_base = x_imag + (size_t)(b_base + wid * 16 + m) * RS + r * S_TOT;

    // raw next-strip payload: 16 f32x4 = 64 VGPRs, kept in flight across compute
    f32x4 rawr[8], rawi[8];

#define LOAD_STRIP(it)                                                    \
    do {                                                                  \
        __builtin_amdgcn_sched_barrier(0);                                \
        const float* pr_ = pr_base + (size_t)(it) * 64 * RS;              \
        const float* pi_ = pi_base + (size_t)(it) * 64 * RS;              \
        _Pragma("unroll")                                                 \
        for (int kk = 0; kk < 4; ++kk) {                                  \
            const int kb = kk * 32 + g * 8;                               \
            rawr[2 * kk]     = *(const f32x4*)(pr_ + kb);                 \
            rawr[2 * kk + 1] = *(const f32x4*)(pr_ + kb + 4);             \
            rawi[2 * kk]     = *(const f32x4*)(pi_ + kb);                 \
            rawi[2 * kk + 1] = *(const f32x4*)(pi_ + kb + 4);             \
        }                                                                 \
        __builtin_amdgcn_sched_barrier(0);                                \
    } while (0)

    // issue strip 0 loads before W staging to hide startup latency
    LOAD_STRIP(0);

    // ---- stage W[r] -> LDS (coalesced fp32 reads, 16B swizzled bf16 writes)
    const float* wr = proj + (size_t)r * (S_TOT * P_TOT);
    #pragma unroll
    for (int i = 0; i < 8; ++i) {
        const int pair = tid + i * 256;
        const int p  = pair & 127;
        const int sc = pair >> 7;  // 0..15
        bf16x8 wv;
        #pragma unroll
        for (int j = 0; j < 8; ++j) {
            wv[j] = (__bf16)wr[(sc * 8 + j) * 128 + p];
        }
        *(bf16x8*)&wlds[p * 128 + ((sc ^ (p & 7)) << 3)] = wv;
    }
    __syncthreads();

    #pragma unroll
    for (int it = 0; it < 4; ++it) {
        // convert current strip raw -> bf16 fragments (raw regs then reusable)
        bf16x8 ar[4], ai[4];
        #pragma unroll
        for (int kk = 0; kk < 4; ++kk) {
            bf16x8 a, b;
            #pragma unroll
            for (int j = 0; j < 4; ++j) {
                a[j]     = (__bf16)rawr[2 * kk][j];
                a[j + 4] = (__bf16)rawr[2 * kk + 1][j];
                b[j]     = (__bf16)rawi[2 * kk][j];
                b[j + 4] = (__bf16)rawi[2 * kk + 1][j];
            }
            ar[kk] = a;
            ai[kk] = b;
        }

        // prefetch next strip while this strip computes (pinned by fences)
        if (it < 3) LOAD_STRIP(it + 1);

        const int b0 = b_base + it * 64 + wid * 16;
        float* po = out + (size_t)(b0 + g * 4) * RP + r * P_TOT + m;

        #pragma unroll
        for (int n = 0; n < 8; ++n) {
            const int p = n * 16 + m;
            f32x4 cr = (f32x4)0.0f;
            f32x4 ci = (f32x4)0.0f;
            #pragma unroll
            for (int kk = 0; kk < 4; ++kk) {
                const int sb = kk * 4 + g;
                const bf16x8 w =
                    *(const bf16x8*)&wlds[p * 128 + ((sb ^ (m & 7)) << 3)];
                cr = __builtin_amdgcn_mfma_f32_16x16x32_bf16(ar[kk], w, cr, 0, 0, 0);
                ci = __builtin_amdgcn_mfma_f32_16x16x32_bf16(ai[kk], w, ci, 0, 0, 0);
            }
            // D mapping (m89): col = lane&15, row = (lane>>4)*4 + j
            #pragma unroll
            for (int j = 0; j < 4; ++j) {
                float re = cr[j];
                float im = ci[j];
                po[(size_t)j * RP + n * 16] = sqrtf(re * re + im * im);
            }
        }
    }
#undef LOAD_STRIP
}

extern "C" void kernel_launch(void* const* d_in, const int* in_sizes, int n_in,
                              void* d_out, int out_size, void* d_ws, size_t ws_size,
                              hipStream_t stream) {
    const float* x_real = (const float*)d_in[0];
    const float* x_imag = (const float*)d_in[1];
    const float* proj   = (const float*)d_in[2];
    float* out = (float*)d_out;

    dim3 grid(R_TOT * BLOCKS_PER_R);  // 2048 blocks
    dim3 block(256);
    cproj_kernel<<<grid, block, 0, stream>>>(x_real, x_imag, proj, out);
}

// Round 5
// 155.823 us; speedup vs baseline: 1.7859x; 1.1213x over previous
//
#include <hip/hip_runtime.h>
#include <hip/hip_bf16.h>
#include <math.h>

// ComplexProjection: out[b,r,p] = | sum_s complex(xr,xi)[b,r,s] * w[r,s,p] |
// B=32768, R=16, S=128, P=128. HBM-bound target (~770 MB).
// R5: 2-phase global_load_lds pipeline (T3-minimum template):
//   - x staged to LDS by hardware DMA (no VGPR liveness fight; prefetch depth
//     lives in the VMEM queue, drained only at the per-strip barrier).
//   - W in registers (8 bf16x8 per wave, one-time L2 loads) -> no W LDS reads
//     (R1-R4's 4.19M bank conflicts were the W path).
//   - source-pre-swizzled staging (chunk ^= row&7 on the per-lane GLOBAL addr,
//     LDS dest linear per rule #21) -> bank-uniform A ds_read_b128.
//   - slab-dense mapping kept (r = blockIdx&15).

typedef __attribute__((ext_vector_type(8))) __bf16 bf16x8;
typedef __attribute__((ext_vector_type(4))) float f32x4;

#define R_TOT 16
#define S_TOT 128
#define P_TOT 128
#define RS 2048            // x row stride (floats)
#define RP 2048            // out row stride (floats)
#define ROWS_PER_BLOCK 256
#define STRIP 16
#define NSTRIPS (ROWS_PER_BLOCK / STRIP)  // 16

typedef const __attribute__((address_space(1))) void* gas_t;
typedef __attribute__((address_space(3))) void* las_t;

__global__ __launch_bounds__(256, 3) void cproj_kernel(
    const float* __restrict__ x_real,
    const float* __restrict__ x_imag,
    const float* __restrict__ proj,
    float* __restrict__ out)
{
    // x double buffer: [buf][arr(re/im)][row][128 floats], rows chunk-swizzled:
    // LDS[row][u] (16B units u=0..31) holds global chunk (u ^ (row&7)).
    __shared__ __attribute__((aligned(16))) float xb[2][2][STRIP][128];

    const int tid  = threadIdx.x;
    const int r    = blockIdx.x & 15;   // co-scheduled blocks span all r
    const int br   = blockIdx.x >> 4;
    const int lane = tid & 63;
    const int wid  = tid >> 6;          // 0..3: owns p-range [32*wid, +32)
    const int m    = lane & 15;
    const int g    = lane >> 4;         // 0..3 k-group / D row group
    const int b_base = br * ROWS_PER_BLOCK;

    // staging split: wave w stages array (w>>1), rows [(w&1)*8, +8) (4 instrs)
    const int st_arr = wid >> 1;
    const int st_r0  = (wid & 1) * 8;
    const float* xsrc = (st_arr == 0) ? x_real : x_imag;

#define STAGE(bufi, strip_)                                                    \
    do {                                                                       \
        _Pragma("unroll")                                                      \
        for (int i = 0; i < 4; ++i) {                                          \
            const int row = st_r0 + 2 * i + (lane >> 5);                       \
            const int gb  = b_base + (strip_) * STRIP + row;                   \
            const float* gp = xsrc + (size_t)gb * RS + r * S_TOT               \
                              + (((lane & 31) ^ (row & 7)) << 2);              \
            __builtin_amdgcn_global_load_lds(                                  \
                (gas_t)gp, (las_t)&xb[bufi][st_arr][st_r0 + 2 * i][0],         \
                16, 0, 0);                                                     \
        }                                                                      \
    } while (0)

    // ---- prologue: issue strip-0 stage first (HBM latency hides under W) ----
    STAGE(0, 0);

    // W fragments in registers: wf[nt][kk], p = wid*32 + nt*16 + m,
    // k = kk*32 + g*8 + j. proj is L2/L3-hot (1 MB total).
    bf16x8 wf[2][4];
    {
        const float* wrp = proj + (size_t)r * (S_TOT * P_TOT) + wid * 32 + m;
        #pragma unroll
        for (int nt = 0; nt < 2; ++nt) {
            #pragma unroll
            for (int kk = 0; kk < 4; ++kk) {
                bf16x8 w;
                #pragma unroll
                for (int j = 0; j < 8; ++j) {
                    w[j] = (__bf16)wrp[(size_t)(kk * 32 + g * 8 + j) * P_TOT
                                       + nt * 16];
                }
                wf[nt][kk] = w;
            }
        }
    }
    __syncthreads();  // drains vmcnt: strip-0 stage + W loads complete

    for (int s = 0; s < NSTRIPS; ++s) {
        const int buf = s & 1;
        if (s + 1 < NSTRIPS) STAGE(buf ^ 1, s + 1);
        __builtin_amdgcn_sched_barrier(0);  // pin stage issue before compute

        // ---- A fragments from LDS (swizzled, bank-uniform b128 reads) ----
        bf16x8 ar[2][4];  // [arr][kk]
        #pragma unroll
        for (int a = 0; a < 2; ++a) {
            #pragma unroll
            for (int kk = 0; kk < 4; ++kk) {
                const int c0 = kk * 8 + 2 * g;          // even
                const int s0 = (c0 ^ (m & 7)) << 2;     // float index of 16B slot
                const int s1 = ((c0 + 1) ^ (m & 7)) << 2;
                f32x4 lo = *(const f32x4*)&xb[buf][a][m][s0];
                f32x4 hi = *(const f32x4*)&xb[buf][a][m][s1];
                bf16x8 t;
                #pragma unroll
                for (int j = 0; j < 4; ++j) {
                    t[j]     = (__bf16)lo[j];
                    t[j + 4] = (__bf16)hi[j];
                }
                ar[a][kk] = t;
            }
        }

        // ---- MFMA: D[b][p], A = x rows, B = W cols ----
        f32x4 acc[2][2];  // [nt][arr]
        #pragma unroll
        for (int nt = 0; nt < 2; ++nt) {
            acc[nt][0] = (f32x4)0.0f;
            acc[nt][1] = (f32x4)0.0f;
        }
        #pragma unroll
        for (int kk = 0; kk < 4; ++kk) {
            #pragma unroll
            for (int nt = 0; nt < 2; ++nt) {
                acc[nt][0] = __builtin_amdgcn_mfma_f32_16x16x32_bf16(
                    ar[0][kk], wf[nt][kk], acc[nt][0], 0, 0, 0);
                acc[nt][1] = __builtin_amdgcn_mfma_f32_16x16x32_bf16(
                    ar[1][kk], wf[nt][kk], acc[nt][1], 0, 0, 0);
            }
        }

        // |z| epilogue in regs
        float ov[2][4];
        #pragma unroll
        for (int nt = 0; nt < 2; ++nt) {
            #pragma unroll
            for (int j = 0; j < 4; ++j) {
                float re = acc[nt][0][j];
                float im = acc[nt][1][j];
                ov[nt][j] = sqrtf(re * re + im * im);
            }
        }

        // barrier = single drain point: waits STAGE(s+1) DMA + all waves'
        // ds_reads of buf (so next iter may overwrite it). Stores go after
        // so their completion never sits on the drain path.
        if (s + 1 < NSTRIPS) __syncthreads();

        // D mapping (m89): col = lane&15 -> p, row = g*4+j -> b
        float* po = out + (size_t)(b_base + s * STRIP + g * 4) * RP
                    + r * P_TOT + wid * 32 + m;
        #pragma unroll
        for (int nt = 0; nt < 2; ++nt) {
            #pragma unroll
            for (int j = 0; j < 4; ++j) {
                po[(size_t)j * RP + nt * 16] = ov[nt][j];
            }
        }
    }
#undef STAGE
}

extern "C" void kernel_launch(void* const* d_in, const int* in_sizes, int n_in,
                              void* d_out, int out_size, void* d_ws, size_t ws_size,
                              hipStream_t stream) {
    const float* x_real = (const float*)d_in[0];
    const float* x_imag = (const float*)d_in[1];
    const float* proj   = (const float*)d_in[2];
    float* out = (float*)d_out;

    dim3 grid(R_TOT * 128);  // 2048 blocks
    dim3 block(256);
    cproj_kernel<<<grid, block, 0, stream>>>(x_real, x_imag, proj, out);
}